// Round 1
// 490.374 us; speedup vs baseline: 1.1210x; 1.1210x over previous
//
#include <hip/hip_runtime.h>
#include <stdint.h>

#define MM 8192   // B*S = 4*2048
#define NN 4096
#define KK 4096

// legacy 128^2 params (fallback paths)
#define BM 128
#define BN 128
#define BK 32
#define WTBLKS 4096   // 64x64 transpose tiles: (4096/64)^2

// 8-phase 256^2 params
#define BM2 256
#define BN2 256
#define BK2 64
#define NT  (KK / BK2)                    // 64 K-tiles
#define NWG ((MM / BM2) * (NN / BN2))     // 512 workgroups

typedef __bf16 bf16x8 __attribute__((ext_vector_type(8)));
typedef float  f32x4  __attribute__((ext_vector_type(4)));

__device__ __forceinline__ unsigned short f2bf(float f) {
    union { float f; uint32_t u; } v; v.f = f;
    uint32_t r = v.u + 0x7fffu + ((v.u >> 16) & 1u);   // RTNE
    return (unsigned short)(r >> 16);
}

__device__ __forceinline__ uint32_t pk2(float lo, float hi) {
    return (uint32_t)f2bf(lo) | ((uint32_t)f2bf(hi) << 16);
}

__device__ __forceinline__ void gld16(const void* g, void* l) {
    __builtin_amdgcn_global_load_lds(
        (const __attribute__((address_space(1))) void*)g,
        (__attribute__((address_space(3))) void*)l, 16, 0, 0);
}

// ---- prep, split for per-kernel rocprof attribution ----
// W (K x N fp32) -> wt (N x K bf16), 64x64 tiles via LDS
__global__ __launch_bounds__(256) void prep_w(
    const float* __restrict__ W, unsigned short* __restrict__ wt)
{
    __shared__ float t[64][65];
    const int b = blockIdx.x;
    const int tid = threadIdx.x;
    const int n0 = (b & 63) * 64;
    const int k0 = (b >> 6) * 64;
    const int kr = tid >> 4;
    const int nf = (tid & 15) * 4;
    #pragma unroll
    for (int p = 0; p < 4; p++) {
        const int k = p * 16 + kr;
        float4 v = *(const float4*)(W + (size_t)(k0 + k) * NN + n0 + nf);
        t[nf + 0][k] = v.x; t[nf + 1][k] = v.y;
        t[nf + 2][k] = v.z; t[nf + 3][k] = v.w;
    }
    __syncthreads();
    const int nr = tid >> 3;
    const int kc = (tid & 7) * 8;
    #pragma unroll
    for (int p = 0; p < 2; p++) {
        const int n = p * 32 + nr;
        uint32_t h[4];
        #pragma unroll
        for (int j = 0; j < 4; j++)
            h[j] = pk2(t[n][kc + 2 * j], t[n][kc + 2 * j + 1]);
        *(uint4*)(wt + (size_t)(n0 + n) * KK + k0 + kc) = *(uint4*)h;
    }
}

// x (fp32) -> xb (bf16), pure streaming cast
__global__ __launch_bounds__(256) void prep_x(
    const float* __restrict__ x, unsigned short* __restrict__ xb)
{
    size_t i = ((size_t)blockIdx.x * 256 + threadIdx.x) * 8;
    float4 a = *(const float4*)(x + i);
    float4 c = *(const float4*)(x + i + 4);
    uint32_t h[4];
    h[0] = pk2(a.x, a.y); h[1] = pk2(a.z, a.w);
    h[2] = pk2(c.x, c.y); h[3] = pk2(c.z, c.w);
    *(uint4*)(xb + i) = *(uint4*)h;
}

// ---- 256^2 8-phase bf16 GEMM (guide §5 template, T1+T2+T3/T4+T5) ----
// A: xb (M x K bf16), Bt: wt (N x K bf16), C = A*Bt^T + bias (fp32).
// Per block: 512 thr = 8 waves (2M x 4N), wave owns 128x64 of C.
// LDS: 2 x (A 32KB + B 32KB) = 128KB double buffer, BK=64.
// Stage chunks per tile (order): Aq0, Bq0, Bq1, Aq1, where
//   Aq(h) = rows [h*64,h*64+64) u [128+h*64, ...): the m-quadrant-h rows of both wave-rows
//   Bq(h) = rows wcol*64 + h*32 .. +32 for all wcol.
// vmcnt ledger (2 loads/chunk/thread): consumption P4:{Aq0,Bq0} P5:{Bq1} P6:{Aq1};
//   staged 4 phases earlier => vmcnt(4) at end of phases 0,1,3,4,5,7 keeps >=2 chunks
//   in flight, never drains. Last iter wrap-stages tile (t+2)&63 to keep ledger uniform;
//   vmcnt(0) after the loop so no global_load_lds is outstanding at endpgm.
// LDS swizzle: 16B slot ^= (row&7); dest of global_load_lds stays LINEAR, the
//   global SOURCE slot is pre-swizzled (both-sides involution, rule #21).

#define BAR()   asm volatile("s_barrier" ::: "memory")
#define VM4()   asm volatile("s_waitcnt vmcnt(4)" ::: "memory")
#define PRIO1() __builtin_amdgcn_s_setprio(1)
#define PRIO0() __builtin_amdgcn_s_setprio(0)

__device__ __forceinline__ void stage2(const unsigned short* __restrict__ gp,
                                       unsigned short* lb, int row0, int kcol,
                                       int ss) {
    const int gs = (ss ^ (row0 & 7)) << 3;      // pre-swizzled global slot
    gld16(gp + (size_t)row0 * KK + kcol + gs, lb + row0 * 64 + ss * 8);
    gld16(gp + (size_t)(row0 + 128) * KK + kcol + gs,
          lb + (row0 + 128) * 64 + ss * 8);
}

#define STA(ca, kcol, BUF) stage2(Ap, &As[BUF][0], sr + (ca) * 64, kcol, ss)
#define STB(cb, kcol, BUF) \
    stage2(Bp, &Bs[BUF][0], (sr & 31) + (cb) * 32 + ((sr >> 5) << 6), kcol, ss)

#define LDA(BUF, mq) { \
    _Pragma("unroll") for (int ii = 0; ii < 4; ++ii) { \
        const unsigned short* p = &As[BUF][(arow0 + (mq) * 64 + ii * 16) * 64]; \
        fa[ii][0] = *(const bf16x8*)(p + sw0); \
        fa[ii][1] = *(const bf16x8*)(p + sw1); } }

#define LDB(FB, BUF, nq) { \
    _Pragma("unroll") for (int jj = 0; jj < 2; ++jj) { \
        const unsigned short* p = &Bs[BUF][(brow0 + (nq) * 32 + jj * 16) * 64]; \
        FB[jj][0] = *(const bf16x8*)(p + sw0); \
        FB[jj][1] = *(const bf16x8*)(p + sw1); } }

#define MFMAQ(mq, nq, FB) { \
    _Pragma("unroll") for (int ks = 0; ks < 2; ++ks) \
    _Pragma("unroll") for (int ii = 0; ii < 4; ++ii) \
    _Pragma("unroll") for (int jj = 0; jj < 2; ++jj) \
        acc[(mq) * 4 + ii][(nq) * 2 + jj] = \
            __builtin_amdgcn_mfma_f32_16x16x32_bf16( \
                fa[ii][ks], FB[jj][ks], acc[(mq) * 4 + ii][(nq) * 2 + jj], \
                0, 0, 0); }

__global__ __launch_bounds__(512, 2) void gemm8p(
    const unsigned short* __restrict__ A,   // M x K bf16
    const unsigned short* __restrict__ Bt,  // N x K bf16
    const float* __restrict__ bias,
    float* __restrict__ C)                  // M x N fp32
{
    __shared__ unsigned short As[2][BM2 * BK2];   // 64 KB
    __shared__ unsigned short Bs[2][BN2 * BK2];   // 64 KB

    const int tid  = threadIdx.x;
    const int lane = tid & 63;
    const int wave = tid >> 6;
    const int wrow = wave >> 2;            // 0..1
    const int wcol = wave & 3;             // 0..3
    const int fmm  = lane & 15;
    const int lsel = lane >> 4;            // 0..3
    const int sw0  = ((lsel ^ (fmm & 7)) << 3);         // k-step 0 slot (ushorts)
    const int sw1  = (((lsel + 4) ^ (fmm & 7)) << 3);   // k-step 1
    const int sr   = tid >> 3;             // staging row-in-chunk
    const int ss   = tid & 7;              // staging 16B slot (linear dest)

    // T1: bijective XCD swizzle, NWG=512 % 8 == 0
    const int bid = blockIdx.x;
    const int swz = ((bid & 7) << 6) + (bid >> 3);
    const int bm  = (swz >> 4) << 8;       // 32 M-tiles
    const int bn  = (swz & 15) << 8;       // 16 N-tiles

    const unsigned short* Ap = A  + (size_t)bm * KK;
    const unsigned short* Bp = Bt + (size_t)bn * KK;

    const int arow0 = wrow * 128 + fmm;
    const int brow0 = wcol * 64 + fmm;

    f32x4  acc[8][4] = {};
    bf16x8 fa[4][2], fb0[2][2], fb1[2][2];

    // prologue: tile 0 -> buf0, same chunk order as in-loop
    STA(0, 0, 0); STB(0, 0, 0); STB(1, 0, 0); STA(1, 0, 0);
    VM4();                                  // Aq0,Bq0 landed; Bq1,Aq1 in flight
    BAR();

    for (int it = 0; it < NT / 2; ++it) {
        const int t   = it << 1;
        const int kc1 = (t + 1) << 6;
        const int kc2 = (((t + 2) & (NT - 1))) << 6;   // wrap keeps ledger uniform

        // ---- tile t (buf0) ----
        // P0
        LDA(0, 0); LDB(fb0, 0, 0);
        STA(0, kc1, 1);
        BAR(); PRIO1(); MFMAQ(0, 0, fb0); PRIO0(); VM4(); BAR();
        // P1
        LDB(fb1, 0, 1);
        STB(0, kc1, 1);
        BAR(); PRIO1(); MFMAQ(0, 1, fb1); PRIO0(); VM4(); BAR();
        // P2
        LDA(0, 1);
        STB(1, kc1, 1);
        BAR(); PRIO1(); MFMAQ(1, 1, fb1); PRIO0(); BAR();
        // P3
        STA(1, kc1, 1);
        BAR(); PRIO1(); MFMAQ(1, 0, fb0); PRIO0(); VM4(); BAR();
        // ---- tile t+1 (buf1) ----
        // P4
        LDA(1, 0); LDB(fb0, 1, 0);
        STA(0, kc2, 0);
        BAR(); PRIO1(); MFMAQ(0, 0, fb0); PRIO0(); VM4(); BAR();
        // P5
        LDB(fb1, 1, 1);
        STB(0, kc2, 0);
        BAR(); PRIO1(); MFMAQ(0, 1, fb1); PRIO0(); VM4(); BAR();
        // P6
        LDA(1, 1);
        STB(1, kc2, 0);
        BAR(); PRIO1(); MFMAQ(1, 1, fb1); PRIO0(); BAR();
        // P7
        STA(1, kc2, 0);
        BAR(); PRIO1(); MFMAQ(1, 0, fb0); PRIO0(); VM4(); BAR();
    }
    asm volatile("s_waitcnt vmcnt(0)" ::: "memory");   // drain before endpgm

    // epilogue: C/D layout col=lane&15, row=(lane>>4)*4+reg [m89/m91]
    // m offset = 16*mi (mi = mq*4+ii), n offset = 16*nj (nj = nq*2+jj)
    const int crow0 = bm + wrow * 128 + lsel * 4;
    const int ccol0 = bn + wcol * 64 + fmm;
    float bv[4];
    #pragma unroll
    for (int nj = 0; nj < 4; ++nj) bv[nj] = bias[ccol0 + nj * 16];
    #pragma unroll
    for (int mi = 0; mi < 8; ++mi) {
        #pragma unroll
        for (int r = 0; r < 4; ++r) {
            float* crow = C + (size_t)(crow0 + mi * 16 + r) * NN + ccol0;
            #pragma unroll
            for (int nj = 0; nj < 4; ++nj)
                crow[nj * 16] = acc[mi][nj][r] + bv[nj];
        }
    }
}

// ---- legacy 128^2 MFMA GEMM (kept for wt-only workspace path) ----
template<bool AFP32>
__global__ __launch_bounds__(256) void gemm_bt(
    const void* __restrict__ Aptr,
    const unsigned short* __restrict__ Bt,
    const float* __restrict__ bias,
    float* __restrict__ C)
{
    __shared__ unsigned short As[BM * BK];
    __shared__ unsigned short Bs[BN * BK];

    const int tid  = threadIdx.x;
    const int lane = tid & 63;
    const int wave = tid >> 6;
    const int wm   = (wave >> 1) * 64;
    const int wn   = (wave & 1)  * 64;

    const int bn = blockIdx.x * BN;
    const int bm = blockIdx.y * BM;

    const int c0 = tid, c1 = tid + 256;
    const int r0 = c0 >> 2, k0o = (c0 & 3) * 8;
    const int r1 = c1 >> 2, k1o = (c1 & 3) * 8;

    const unsigned short* b0 = Bt + (size_t)(bn + r0) * KK + k0o;
    const unsigned short* b1 = Bt + (size_t)(bn + r1) * KK + k1o;
    unsigned short* asl0 = &As[c0 * 8]; unsigned short* asl1 = &As[c1 * 8];
    unsigned short* bsl0 = &Bs[c0 * 8]; unsigned short* bsl1 = &Bs[c1 * 8];

    const unsigned short* a0h = nullptr; const unsigned short* a1h = nullptr;
    const float* a0f = nullptr; const float* a1f = nullptr;
    if constexpr (AFP32) {
        a0f = (const float*)Aptr + (size_t)(bm + r0) * KK + k0o;
        a1f = (const float*)Aptr + (size_t)(bm + r1) * KK + k1o;
    } else {
        a0h = (const unsigned short*)Aptr + (size_t)(bm + r0) * KK + k0o;
        a1h = (const unsigned short*)Aptr + (size_t)(bm + r1) * KK + k1o;
    }

    const int fm = lane & 15;
    const int fk = (lane >> 4) * 8;

    f32x4 acc[4][4] = {};

    for (int kk = 0; kk < KK; kk += BK) {
        __syncthreads();
        if constexpr (AFP32) {
            float4 f00 = *(const float4*)(a0f + kk);
            float4 f01 = *(const float4*)(a0f + kk + 4);
            float4 f10 = *(const float4*)(a1f + kk);
            float4 f11 = *(const float4*)(a1f + kk + 4);
            gld16(b0 + kk, bsl0);
            gld16(b1 + kk, bsl1);
            uint4 p0, p1;
            p0.x = pk2(f00.x, f00.y); p0.y = pk2(f00.z, f00.w);
            p0.z = pk2(f01.x, f01.y); p0.w = pk2(f01.z, f01.w);
            p1.x = pk2(f10.x, f10.y); p1.y = pk2(f10.z, f10.w);
            p1.z = pk2(f11.x, f11.y); p1.w = pk2(f11.z, f11.w);
            *(uint4*)asl0 = p0;
            *(uint4*)asl1 = p1;
        } else {
            gld16(a0h + kk, asl0);
            gld16(a1h + kk, asl1);
            gld16(b0 + kk, bsl0);
            gld16(b1 + kk, bsl1);
        }
        __syncthreads();

        bf16x8 fa[4], fb[4];
        #pragma unroll
        for (int i = 0; i < 4; i++)
            fa[i] = *(bf16x8*)&As[(wm + i * 16 + fm) * BK + fk];
        #pragma unroll
        for (int j = 0; j < 4; j++)
            fb[j] = *(bf16x8*)&Bs[(wn + j * 16 + fm) * BK + fk];
        #pragma unroll
        for (int i = 0; i < 4; i++)
            #pragma unroll
            for (int j = 0; j < 4; j++)
                acc[i][j] = __builtin_amdgcn_mfma_f32_16x16x32_bf16(
                    fa[i], fb[j], acc[i][j], 0, 0, 0);
    }

    const int row4 = (lane >> 4) * 4;
    float bv[4];
    #pragma unroll
    for (int j = 0; j < 4; j++) bv[j] = bias[bn + wn + j * 16 + fm];
    #pragma unroll
    for (int i = 0; i < 4; i++) {
        #pragma unroll
        for (int r = 0; r < 4; r++) {
            const int m = bm + wm + i * 16 + row4 + r;
            float* crow = C + (size_t)m * NN + bn + wn + fm;
            #pragma unroll
            for (int j = 0; j < 4; j++)
                crow[j * 16] = acc[i][j][r] + bv[j];
        }
    }
}

// ---- insurance fallback: fp32 vector GEMM, zero workspace ----
__global__ __launch_bounds__(256) void gemm_f32(
    const float* __restrict__ A, const float* __restrict__ W,
    const float* __restrict__ bias, float* __restrict__ C)
{
    __shared__ float As[16][68];
    __shared__ float Ws[16][68];
    const int tid = threadIdx.x;
    const int bm = blockIdx.y * 64, bn = blockIdx.x * 64;
    const int tx = tid & 15, ty = tid >> 4;
    const int am = tid >> 2, ak = (tid & 3) * 4;
    const int wk = tid >> 4, wn = (tid & 15) * 4;
    float acc[4][4] = {};
    for (int kk = 0; kk < KK; kk += 16) {
        float4 av = *(const float4*)(A + (size_t)(bm + am) * KK + kk + ak);
        float4 wv = *(const float4*)(W + (size_t)(kk + wk) * NN + bn + wn);
        __syncthreads();
        As[ak + 0][am] = av.x; As[ak + 1][am] = av.y;
        As[ak + 2][am] = av.z; As[ak + 3][am] = av.w;
        Ws[wk][wn] = wv.x; Ws[wk][wn + 1] = wv.y;
        Ws[wk][wn + 2] = wv.z; Ws[wk][wn + 3] = wv.w;
        __syncthreads();
        #pragma unroll
        for (int k = 0; k < 16; k++) {
            float a[4], b[4];
            #pragma unroll
            for (int i = 0; i < 4; i++) a[i] = As[k][ty * 4 + i];
            #pragma unroll
            for (int j = 0; j < 4; j++) b[j] = Ws[k][tx * 4 + j];
            #pragma unroll
            for (int i = 0; i < 4; i++)
                #pragma unroll
                for (int j = 0; j < 4; j++)
                    acc[i][j] += a[i] * b[j];
        }
    }
    #pragma unroll
    for (int i = 0; i < 4; i++)
        #pragma unroll
        for (int j = 0; j < 4; j++)
            C[(size_t)(bm + ty * 4 + i) * NN + bn + tx * 4 + j] =
                acc[i][j] + bias[bn + tx * 4 + j];
}

extern "C" void kernel_launch(void* const* d_in, const int* in_sizes, int n_in,
                              void* d_out, int out_size, void* d_ws, size_t ws_size,
                              hipStream_t stream) {
    const float* x    = (const float*)d_in[0];
    const float* W    = (const float*)d_in[1];
    const float* bias = (const float*)d_in[2];
    float* out = (float*)d_out;

    const size_t need_wt   = (size_t)NN * KK * 2;              // 32 MiB
    const size_t need_full = need_wt + (size_t)MM * KK * 2;    // 96 MiB

    if (ws_size >= need_full) {
        // fast path: W transpose+cast, x cast, then 256^2 8-phase GEMM
        unsigned short* wt = (unsigned short*)d_ws;
        unsigned short* xb = wt + (size_t)NN * KK;
        prep_w<<<WTBLKS, 256, 0, stream>>>(W, wt);
        prep_x<<<(int)((size_t)MM * KK / 2048), 256, 0, stream>>>(x, xb);
        gemm8p<<<NWG, 512, 0, stream>>>(xb, wt, bias, out);
    } else if (ws_size >= need_wt) {
        unsigned short* wt = (unsigned short*)d_ws;
        prep_w<<<WTBLKS, 256, 0, stream>>>(W, wt);
        gemm_bt<true><<<dim3(NN / BN, MM / BM), 256, 0, stream>>>(x, wt, bias, out);
    } else {
        gemm_f32<<<dim3(NN / 64, MM / 64), 256, 0, stream>>>(x, W, bias, out);
    }
}